// Round 6
// baseline (435.388 us; speedup 1.0000x reference)
//
#include <hip/hip_runtime.h>
#include <cmath>

#define BB 64
#define NN 883
#define NP 896      // N padded to multiple of 64
#define EE 10
#define CC 66
#define KP 160      // A'/W' padded K: [0,66)=xs|W0+W1, [80,146)=-d*y|W1, rest 0

typedef __attribute__((ext_vector_type(8))) short bf16x8;
typedef __attribute__((ext_vector_type(4))) float f32x4;

__device__ __forceinline__ float sigmoidf_(float v) { return 1.f / (1.f + expf(-v)); }

// fp32 -> bf16 round-to-nearest-even
__device__ __forceinline__ unsigned short f2bf(float f) {
  unsigned int u = __float_as_uint(f);
  u = u + 0x7FFFu + ((u >> 16) & 1u);
  return (unsigned short)(u >> 16);
}
__device__ __forceinline__ float bf2f(unsigned short h) {
  return __uint_as_float(((unsigned int)h) << 16);
}

// ---------------- K1: concat + hyper-MLP + nodevec; writes Acat[0..79] + nvP --------
template<int PHASE>
__global__ __launch_bounds__(256) void k1_hyper(
    const float* __restrict__ x, const float* __restrict__ state,
    const float* __restrict__ zr, const float* __restrict__ emb,
    const float* __restrict__ tme, const float* __restrict__ day,
    const float* __restrict__ spd, const float* __restrict__ occ,
    const float* __restrict__ w1, const float* __restrict__ b1,
    const float* __restrict__ w2, const float* __restrict__ b2,
    const float* __restrict__ w3, const float* __restrict__ b3,
    unsigned short* __restrict__ Acat, unsigned short* __restrict__ nvP) {
  int idx = blockIdx.x * 256 + threadIdx.x;   // over BB*NP
  if (idx >= BB * NP) return;
  int b = idx / NP, n = idx - b * NP;
  if (n >= NN) {  // zero-pad row of nvP (MFMA B-frags must read zeros)
    *(uint4*)&nvP[(size_t)idx * 16] = make_uint4(0, 0, 0, 0);
    *(uint4*)&nvP[(size_t)idx * 16 + 8] = make_uint4(0, 0, 0, 0);
    return;
  }
  int bn = b * NN + n;

  float xsr[CC];
  xsr[0] = x[bn * 2 + 0];
  xsr[1] = x[bn * 2 + 1];
#pragma unroll
  for (int j = 0; j < 64; ++j) {
    float s = state[bn * 64 + j];
    if (PHASE == 1) s *= zr[(size_t)bn * 128 + j];   // z = first half of sigmoid(z_r)
    xsr[2 + j] = s;
  }
  // write xs (bf16) into Acat slots [0,80) (66 real + 14 zero pad)
  {
    unsigned short a16[80];
#pragma unroll
    for (int c = 0; c < CC; ++c) a16[c] = f2bf(xsr[c]);
#pragma unroll
    for (int c = CC; c < 80; ++c) a16[c] = 0;
#pragma unroll
    for (int k = 0; k < 10; ++k) {
      unsigned int w0 = (unsigned int)a16[8 * k + 0] | ((unsigned int)a16[8 * k + 1] << 16);
      unsigned int w1 = (unsigned int)a16[8 * k + 2] | ((unsigned int)a16[8 * k + 3] << 16);
      unsigned int w2_ = (unsigned int)a16[8 * k + 4] | ((unsigned int)a16[8 * k + 5] << 16);
      unsigned int w3_ = (unsigned int)a16[8 * k + 6] | ((unsigned int)a16[8 * k + 7] << 16);
      *(uint4*)&Acat[(size_t)bn * KP + 8 * k] = make_uint4(w0, w1, w2_, w3_);
    }
  }

  float h1[16];
#pragma unroll
  for (int j = 0; j < 16; ++j) h1[j] = b1[j];
#pragma unroll
  for (int i = 0; i < CC; ++i) {
    float xv = xsr[i];
#pragma unroll
    for (int j = 0; j < 16; ++j) h1[j] = fmaf(xv, w1[i * 16 + j], h1[j]);
  }
#pragma unroll
  for (int j = 0; j < 16; ++j) h1[j] = sigmoidf_(h1[j]);

  float h2[2];
#pragma unroll
  for (int j = 0; j < 2; ++j) {
    float s = b2[j];
#pragma unroll
    for (int i = 0; i < 16; ++i) s = fmaf(h1[i], w2[i * 2 + j], s);
    h2[j] = sigmoidf_(s);
  }

  unsigned short nv16[16];
#pragma unroll
  for (int e = 0; e < EE; ++e) {
    float f = b3[e] + h2[0] * w3[e] + h2[1] * w3[EE + e];
    int be = bn * EE + e;
    float dyn = emb[n * EE + e] * tme[be] * day[be] * spd[be] * occ[be];
    nv16[e] = f2bf(tanhf(dyn * f));
  }
#pragma unroll
  for (int e = EE; e < 16; ++e) nv16[e] = 0;
  unsigned int w[8];
#pragma unroll
  for (int k = 0; k < 8; ++k)
    w[k] = (unsigned int)nv16[2 * k] | ((unsigned int)nv16[2 * k + 1] << 16);
  *(uint4*)&nvP[(size_t)idx * 16]     = make_uint4(w[0], w[1], w[2], w[3]);
  *(uint4*)&nvP[(size_t)idx * 16 + 8] = make_uint4(w[4], w[5], w[6], w[7]);
}

// ---------------- K2: dd rowsum via MFMA + fused rsqrt + xsdT build ----------------
// grid (14, 64), 256 thr = 4 waves; wave w owns n-rows [nt*64+w*16, +16)
__global__ __launch_bounds__(256) void k2_deg(const unsigned short* __restrict__ nvP,
                                              const unsigned short* __restrict__ Acat,
                                              float* __restrict__ d_g,
                                              unsigned short* __restrict__ xsdT) {
  int nt = blockIdx.x, b = blockIdx.y;
  int t = threadIdx.x, wid = t >> 6, lane = t & 63;
  int col = lane & 15, q = lane >> 4;
  int n16 = nt * 64 + wid * 16;
  __shared__ float tile[64][67];
  __shared__ float d_s[64];

  const unsigned short* nvb = nvP + (size_t)b * NP * 16;
  bf16x8 zf = {0, 0, 0, 0, 0, 0, 0, 0};
  bf16x8 anv = zf;
  if (q < 2) anv = *(const bf16x8*)&nvb[(size_t)(n16 + col) * 16 + q * 8];

  float rs[4] = {0.f, 0.f, 0.f, 0.f};
  bf16x8 cur = zf, nxt = zf;
  if (q < 2) cur = *(const bf16x8*)&nvb[(size_t)col * 16 + q * 8];
  for (int mb = 0; mb < NP; mb += 16) {
    if (q < 2 && mb + 16 < NP)
      nxt = *(const bf16x8*)&nvb[(size_t)(mb + 16 + col) * 16 + q * 8];
    f32x4 z = {0.f, 0.f, 0.f, 0.f};
    f32x4 g = __builtin_amdgcn_mfma_f32_16x16x32_bf16(anv, cur, z, 0, 0, 0);
#pragma unroll
    for (int r = 0; r < 4; ++r) rs[r] += fmaxf(g[r], 0.f);
    cur = nxt;
  }
#pragma unroll
  for (int off = 1; off < 16; off <<= 1) {
#pragma unroll
    for (int r = 0; r < 4; ++r) rs[r] += __shfl_xor(rs[r], off);
  }
  if (col == 0) {
#pragma unroll
    for (int r = 0; r < 4; ++r) {
      int n = n16 + q * 4 + r;
      float dv = (n < NN) ? rsqrtf(rs[r]) : 0.f;
      d_g[b * NP + n] = dv;
      d_s[wid * 16 + q * 4 + r] = dv;
    }
  }
  __syncthreads();

  // fused k2b: xsdT[b][c][m] = bf16(d[m] * xs[m][c]) for this block's 64 m-rows
  int mb = nt * 64;
  for (int idx = t; idx < 64 * CC; idx += 256) {
    int ml = idx / CC, c = idx - ml * CC;
    int m = mb + ml;
    float v = 0.f;
    if (m < NN) v = bf2f(Acat[((size_t)(b * NN + m)) * KP + c]);
    tile[ml][c] = v * d_s[ml];
  }
  __syncthreads();
  for (int idx = t; idx < CC * 64; idx += 256) {
    int c = idx >> 6, ml = idx & 63;
    xsdT[((size_t)(b * CC) + c) * NP + mb + ml] = f2bf(tile[ml][c]);
  }
}

// ---------------- K3: Acat[bn][80+c] = -d[n] * sum_m relu(nv.nv)[n,m] * xsd[m,c] -----
// Software-pipelined: double-buffered wave-private LDS A-tile; stage1(i) overlaps
// stage2(i-1); nv/xsd prefetched one iteration ahead. No __syncthreads in main loop.
__global__ __launch_bounds__(256) void k3_agg(const unsigned short* __restrict__ nvP,
                                              const float* __restrict__ d_g,
                                              const unsigned short* __restrict__ xsdT,
                                              unsigned short* __restrict__ Acat) {
  int nt = blockIdx.x, b = blockIdx.y, t = threadIdx.x;
  int wid = t >> 6, lane = t & 63, col = lane & 15, q = lane >> 4;
  int n16 = nt * 64 + wid * 16;
  // per-wave double buffer: [buf][n(16) rows][m(32)+8 pad] bf16
  __shared__ __align__(16) unsigned short As[4][2][16 * 40];
  unsigned short* wAs0 = As[wid][0];
  unsigned short* wAs1 = As[wid][1];

  const unsigned short* nvb = nvP + (size_t)b * NP * 16;
  const unsigned short* xb = xsdT + (size_t)b * CC * NP;

  bf16x8 zf = {0, 0, 0, 0, 0, 0, 0, 0};
  bf16x8 anv = zf;
  if (q < 2) anv = *(const bf16x8*)&nvb[(size_t)(n16 + col) * 16 + q * 8];

  f32x4 acc[5];
#pragma unroll
  for (int ct = 0; ct < 5; ++ct) acc[ct] = (f32x4){0.f, 0.f, 0.f, 0.f};

  int cg[5];
  bool cok[5];
#pragma unroll
  for (int ct = 0; ct < 5; ++ct) { cg[ct] = ct * 16 + col; cok[ct] = cg[ct] < CC; }

  bf16x8 nv0 = zf, nv1 = zf, nv0n = zf, nv1n = zf;
  bf16x8 xs2[5], xsn[5];

  if (q < 2) {
    nv0 = *(const bf16x8*)&nvb[(size_t)(0 + col) * 16 + q * 8];
    nv1 = *(const bf16x8*)&nvb[(size_t)(16 + col) * 16 + q * 8];
  }

  // ---- iter 0 (peeled): prefetch + stage1(0) only ----
  {
    if (q < 2) {
      nv0n = *(const bf16x8*)&nvb[(size_t)(32 + col) * 16 + q * 8];
      nv1n = *(const bf16x8*)&nvb[(size_t)(48 + col) * 16 + q * 8];
    }
#pragma unroll
    for (int ct = 0; ct < 5; ++ct)
      xsn[ct] = cok[ct] ? *(const bf16x8*)&xb[(size_t)cg[ct] * NP + 0 + q * 8] : zf;
    f32x4 z = {0.f, 0.f, 0.f, 0.f};
    f32x4 g0 = __builtin_amdgcn_mfma_f32_16x16x32_bf16(nv0, anv, z, 0, 0, 0);
    f32x4 g1 = __builtin_amdgcn_mfma_f32_16x16x32_bf16(nv1, anv, z, 0, 0, 0);
    // C-layout (transposed stage1): lane(q,col) holds G1T[m=mf*16+q*4+r][n=col]
    unsigned int a0 = (unsigned int)f2bf(fmaxf(g0[0], 0.f)) | ((unsigned int)f2bf(fmaxf(g0[1], 0.f)) << 16);
    unsigned int a1 = (unsigned int)f2bf(fmaxf(g0[2], 0.f)) | ((unsigned int)f2bf(fmaxf(g0[3], 0.f)) << 16);
    unsigned int b0 = (unsigned int)f2bf(fmaxf(g1[0], 0.f)) | ((unsigned int)f2bf(fmaxf(g1[1], 0.f)) << 16);
    unsigned int b1 = (unsigned int)f2bf(fmaxf(g1[2], 0.f)) | ((unsigned int)f2bf(fmaxf(g1[3], 0.f)) << 16);
    *(uint2*)&wAs0[col * 40 + 0 + q * 4] = make_uint2(a0, a1);
    *(uint2*)&wAs0[col * 40 + 16 + q * 4] = make_uint2(b0, b1);
    nv0 = nv0n; nv1 = nv1n;
#pragma unroll
    for (int ct = 0; ct < 5; ++ct) xs2[ct] = xsn[ct];
  }

  // ---- main loop: iter i does stage1(i) + stage2(i-1) ----
  for (int i = 1; i < 28; ++i) {
    unsigned short* curB = (i & 1) ? wAs1 : wAs0;
    unsigned short* prvB = (i & 1) ? wAs0 : wAs1;
    // afr: A-tile of stage2(i-1), written in iter i-1 -> available now
    bf16x8 afr = *(const bf16x8*)&prvB[col * 40 + q * 8];
    // prefetch nv for block i+1
    int mbn = (i + 1) * 32;
    if (i < 27 && q < 2) {
      nv0n = *(const bf16x8*)&nvb[(size_t)(mbn + col) * 16 + q * 8];
      nv1n = *(const bf16x8*)&nvb[(size_t)(mbn + 16 + col) * 16 + q * 8];
    }
    // prefetch xsd for block i (consumed next iter)
    int mb = i * 32;
#pragma unroll
    for (int ct = 0; ct < 5; ++ct)
      xsn[ct] = cok[ct] ? *(const bf16x8*)&xb[(size_t)cg[ct] * NP + mb + q * 8] : zf;
    // stage1(i)
    f32x4 z = {0.f, 0.f, 0.f, 0.f};
    f32x4 g0 = __builtin_amdgcn_mfma_f32_16x16x32_bf16(nv0, anv, z, 0, 0, 0);
    f32x4 g1 = __builtin_amdgcn_mfma_f32_16x16x32_bf16(nv1, anv, z, 0, 0, 0);
    unsigned int a0 = (unsigned int)f2bf(fmaxf(g0[0], 0.f)) | ((unsigned int)f2bf(fmaxf(g0[1], 0.f)) << 16);
    unsigned int a1 = (unsigned int)f2bf(fmaxf(g0[2], 0.f)) | ((unsigned int)f2bf(fmaxf(g0[3], 0.f)) << 16);
    unsigned int b0 = (unsigned int)f2bf(fmaxf(g1[0], 0.f)) | ((unsigned int)f2bf(fmaxf(g1[1], 0.f)) << 16);
    unsigned int b1 = (unsigned int)f2bf(fmaxf(g1[2], 0.f)) | ((unsigned int)f2bf(fmaxf(g1[3], 0.f)) << 16);
    *(uint2*)&curB[col * 40 + 0 + q * 4] = make_uint2(a0, a1);
    *(uint2*)&curB[col * 40 + 16 + q * 4] = make_uint2(b0, b1);
    // stage2(i-1)
#pragma unroll
    for (int ct = 0; ct < 5; ++ct)
      acc[ct] = __builtin_amdgcn_mfma_f32_16x16x32_bf16(afr, xs2[ct], acc[ct], 0, 0, 0);
    // rotate
    nv0 = nv0n; nv1 = nv1n;
#pragma unroll
    for (int ct = 0; ct < 5; ++ct) xs2[ct] = xsn[ct];
  }

  // ---- epilogue: stage2(27), buffer 27&1 = 1 ----
  {
    bf16x8 afr = *(const bf16x8*)&wAs1[col * 40 + q * 8];
#pragma unroll
    for (int ct = 0; ct < 5; ++ct)
      acc[ct] = __builtin_amdgcn_mfma_f32_16x16x32_bf16(afr, xs2[ct], acc[ct], 0, 0, 0);
  }

  float dn[4];
#pragma unroll
  for (int r = 0; r < 4; ++r) dn[r] = d_g[b * NP + n16 + q * 4 + r];
#pragma unroll
  for (int ct = 0; ct < 5; ++ct) {
    int c = ct * 16 + col;   // c in [0,80): zeros beyond 65 land in the pad slots
#pragma unroll
    for (int r = 0; r < 4; ++r) {
      int n = n16 + q * 4 + r;
      if (n < NN)
        Acat[((size_t)(b * NN) + n) * KP + 80 + c] = f2bf(-(acc[ct][r] * dn[r]));
    }
  }
}

// ---------------- K4b: out[b,o] = act( A'[b,:] . W'[o,:] + bias[o] ) via MFMA --------
// grid (NN); 256 thr = 4 waves (wave = 16 b-rows); W' built in LDS per block
template<int OT, bool GATE>
__global__ __launch_bounds__(256) void k4b_gemm(
    const float* __restrict__ emb, const float* __restrict__ wpool,
    const float* __restrict__ bpool, const unsigned short* __restrict__ Acat,
    float* __restrict__ zr_w,
    const float* __restrict__ state, const float* __restrict__ zr_r,
    float* __restrict__ out) {
  int n = blockIdx.x, t = threadIdx.x;
  __shared__ __align__(16) unsigned short Ws[OT * 168];  // [o][k], 84-word rows
  __shared__ float bias_s[OT];

  // ---- W' build: W0+W1 at k=i, W1 at k=80+i ----
  const int OG = OT / 4;            // o-groups of 4 (float4 over o)
  int og = t % OG, ti = t / OG;     // ti strides i
  int o4 = og * 4;
  float em[EE];
#pragma unroll
  for (int e = 0; e < EE; ++e) em[e] = emb[n * EE + e];

  for (int i = ti; i < CC; i += 256 / OG) {
    float4 s0 = make_float4(0.f, 0.f, 0.f, 0.f);
    float4 s1 = make_float4(0.f, 0.f, 0.f, 0.f);
#pragma unroll
    for (int e = 0; e < EE; ++e) {
      float4 w0 = *(const float4*)&wpool[(((size_t)(e * 2 + 0) * CC + i)) * OT + o4];
      float4 w1 = *(const float4*)&wpool[(((size_t)(e * 2 + 1) * CC + i)) * OT + o4];
      s0.x = fmaf(em[e], w0.x, s0.x); s0.y = fmaf(em[e], w0.y, s0.y);
      s0.z = fmaf(em[e], w0.z, s0.z); s0.w = fmaf(em[e], w0.w, s0.w);
      s1.x = fmaf(em[e], w1.x, s1.x); s1.y = fmaf(em[e], w1.y, s1.y);
      s1.z = fmaf(em[e], w1.z, s1.z); s1.w = fmaf(em[e], w1.w, s1.w);
    }
    Ws[(o4 + 0) * 168 + i] = f2bf(s0.x + s1.x);
    Ws[(o4 + 1) * 168 + i] = f2bf(s0.y + s1.y);
    Ws[(o4 + 2) * 168 + i] = f2bf(s0.z + s1.z);
    Ws[(o4 + 3) * 168 + i] = f2bf(s0.w + s1.w);
    Ws[(o4 + 0) * 168 + 80 + i] = f2bf(s1.x);
    Ws[(o4 + 1) * 168 + 80 + i] = f2bf(s1.y);
    Ws[(o4 + 2) * 168 + 80 + i] = f2bf(s1.z);
    Ws[(o4 + 3) * 168 + 80 + i] = f2bf(s1.w);
  }
  // zero pad slots k in [66,80) and [146,160)
  for (int idx = t; idx < OT * 14; idx += 256) {
    int o = idx / 14, kk = idx - o * 14;
    Ws[o * 168 + 66 + kk] = 0;
    Ws[o * 168 + 146 + kk] = 0;
  }
  if (t < OT) {
    float s = 0.f;
#pragma unroll
    for (int e = 0; e < EE; ++e) s = fmaf(em[e], bpool[e * OT + t], s);
    bias_s[t] = s;
  }
  __syncthreads();

  // ---- GEMM: 4 waves x (16b x OT), K=160 ----
  int wid = t >> 6, lane = t & 63, col = lane & 15, q = lane >> 4;
  int bA = wid * 16 + col;   // A-frag row = batch index
  f32x4 acc[OT / 16];
#pragma unroll
  for (int ot = 0; ot < OT / 16; ++ot) acc[ot] = (f32x4){0.f, 0.f, 0.f, 0.f};

#pragma unroll
  for (int ks = 0; ks < 5; ++ks) {
    bf16x8 af = *(const bf16x8*)&Acat[((size_t)(bA * NN + n)) * KP + ks * 32 + q * 8];
#pragma unroll
    for (int ot = 0; ot < OT / 16; ++ot) {
      bf16x8 bf = *(const bf16x8*)&Ws[(ot * 16 + col) * 168 + ks * 32 + q * 8];
      acc[ot] = __builtin_amdgcn_mfma_f32_16x16x32_bf16(af, bf, acc[ot], 0, 0, 0);
    }
  }

#pragma unroll
  for (int ot = 0; ot < OT / 16; ++ot) {
    int o = ot * 16 + col;
    float bia = bias_s[o];
#pragma unroll
    for (int r = 0; r < 4; ++r) {
      int bb = wid * 16 + q * 4 + r;
      float v = acc[ot][r] + bia;
      if (GATE) {
        zr_w[((size_t)(bb * NN + n)) * 128 + o] = sigmoidf_(v);
      } else {
        float hc = tanhf(v);
        float rr = zr_r[((size_t)(bb * NN + n)) * 128 + 64 + o];
        float st = state[((size_t)(bb * NN + n)) * 64 + o];
        out[((size_t)(bb * NN + n)) * 64 + o] = fmaf(rr, st - hc, hc);
      }
    }
  }
}

extern "C" void kernel_launch(void* const* d_in, const int* in_sizes, int n_in,
                              void* d_out, int out_size, void* d_ws, size_t ws_size,
                              hipStream_t stream) {
  const float* x     = (const float*)d_in[0];
  const float* state = (const float*)d_in[1];
  const float* emb   = (const float*)d_in[2];
  const float* tme   = (const float*)d_in[3];
  const float* day   = (const float*)d_in[4];
  const float* spd   = (const float*)d_in[5];
  const float* occ   = (const float*)d_in[6];
  const float* gwp   = (const float*)d_in[7];
  const float* gbp   = (const float*)d_in[8];
  const float* gw1   = (const float*)d_in[9];
  const float* gb1   = (const float*)d_in[10];
  const float* gw2   = (const float*)d_in[11];
  const float* gb2   = (const float*)d_in[12];
  const float* gw3   = (const float*)d_in[13];
  const float* gb3   = (const float*)d_in[14];
  const float* uwp   = (const float*)d_in[15];
  const float* ubp   = (const float*)d_in[16];
  const float* uw1   = (const float*)d_in[17];
  const float* ub1   = (const float*)d_in[18];
  const float* uw2   = (const float*)d_in[19];
  const float* ub2   = (const float*)d_in[20];
  const float* uw3   = (const float*)d_in[21];
  const float* ub3   = (const float*)d_in[22];

  char* w = (char*)d_ws;
  unsigned short* Acat = (unsigned short*)w;  w += (size_t)BB * NN * KP * 2;  // 18.08 MB
  unsigned short* nvP  = (unsigned short*)w;  w += (size_t)BB * NP * 16 * 2;  // 1.84 MB
  unsigned short* xsdT = (unsigned short*)w;  w += (size_t)BB * CC * NP * 2;  // 7.57 MB
  float* d_g  = (float*)w;  w += (size_t)BB * NP * 4;
  float* zr   = (float*)w;  w += (size_t)BB * NN * 128 * 4;                   // 28.93 MB

  dim3 b256(256);
  dim3 gK1((BB * NP) / 256);      // 224
  dim3 gK2(14, BB);
  dim3 gK4(NN);

  // phase A (gate)
  k1_hyper<0><<<gK1, b256, 0, stream>>>(x, state, zr, emb, tme, day, spd, occ,
                                        gw1, gb1, gw2, gb2, gw3, gb3, Acat, nvP);
  k2_deg<<<gK2, b256, 0, stream>>>(nvP, Acat, d_g, xsdT);
  k3_agg<<<gK2, b256, 0, stream>>>(nvP, d_g, xsdT, Acat);
  k4b_gemm<128, true><<<gK4, b256, 0, stream>>>(emb, gwp, gbp, Acat, zr,
                                                nullptr, nullptr, nullptr);
  // phase B (update)
  k1_hyper<1><<<gK1, b256, 0, stream>>>(x, state, zr, emb, tme, day, spd, occ,
                                        uw1, ub1, uw2, ub2, uw3, ub3, Acat, nvP);
  k2_deg<<<gK2, b256, 0, stream>>>(nvP, Acat, d_g, xsdT);
  k3_agg<<<gK2, b256, 0, stream>>>(nvP, d_g, xsdT, Acat);
  k4b_gemm<64, false><<<gK4, b256, 0, stream>>>(emb, uwp, ubp, Acat, nullptr,
                                                state, zr, (float*)d_out);
}

// Round 7
// 355.065 us; speedup vs baseline: 1.2262x; 1.2262x over previous
//
#include <hip/hip_runtime.h>
#include <cmath>

#define BB 64
#define NN 883
#define NP 896      // N padded to multiple of 64
#define EE 10
#define CC 66
#define KP 160      // A'/W' padded K: [0,66)=xs|W0+W1, [80,146)=-d*y|W1, rest 0
#define NT16 56     // NP/16 tiles
#define MB32 28     // NP/32 blocks

typedef __attribute__((ext_vector_type(8))) short bf16x8;
typedef __attribute__((ext_vector_type(4))) float f32x4;

__device__ __forceinline__ float sigmoidf_(float v) { return 1.f / (1.f + expf(-v)); }

// fp32 -> bf16 round-to-nearest-even
__device__ __forceinline__ unsigned short f2bf(float f) {
  unsigned int u = __float_as_uint(f);
  u = u + 0x7FFFu + ((u >> 16) & 1u);
  return (unsigned short)(u >> 16);
}
__device__ __forceinline__ float bf2f(unsigned short h) {
  return __uint_as_float(((unsigned int)h) << 16);
}
// relu + pack two fp32 -> bf16x2 word
__device__ __forceinline__ unsigned int pkrelu(float a, float b) {
  return (unsigned int)f2bf(fmaxf(a, 0.f)) | ((unsigned int)f2bf(fmaxf(b, 0.f)) << 16);
}

// nv2 layout: [b][n/16 tile][slot = (n%16)*2 + q(0,1)][8 e]  (16B per slot)
// xsd2 layout: [b][m/32 blk][ct(5)][q(4)][col(16)][8 m]      (16B per (q,col))

// ---------------- K1: concat + hyper-MLP + nodevec; writes Acat[0..79] + nv2 --------
template<int PHASE>
__global__ __launch_bounds__(256) void k1_hyper(
    const float* __restrict__ x, const float* __restrict__ state,
    const float* __restrict__ zr, const float* __restrict__ emb,
    const float* __restrict__ tme, const float* __restrict__ day,
    const float* __restrict__ spd, const float* __restrict__ occ,
    const float* __restrict__ w1, const float* __restrict__ b1,
    const float* __restrict__ w2, const float* __restrict__ b2,
    const float* __restrict__ w3, const float* __restrict__ b3,
    unsigned short* __restrict__ Acat, unsigned short* __restrict__ nv2) {
  int idx = blockIdx.x * 256 + threadIdx.x;   // over BB*NP
  if (idx >= BB * NP) return;
  int b = idx / NP, n = idx - b * NP;
  size_t slot = ((size_t)(b * NT16 + (n >> 4)) * 32 + (n & 15) * 2) * 8;
  if (n >= NN) {  // zero-pad row (MFMA frags must read zeros)
    *(uint4*)&nv2[slot] = make_uint4(0, 0, 0, 0);
    *(uint4*)&nv2[slot + 8] = make_uint4(0, 0, 0, 0);
    return;
  }
  int bn = b * NN + n;

  float xsr[CC];
  xsr[0] = x[bn * 2 + 0];
  xsr[1] = x[bn * 2 + 1];
#pragma unroll
  for (int j = 0; j < 64; ++j) {
    float s = state[bn * 64 + j];
    if (PHASE == 1) s *= zr[(size_t)bn * 128 + j];   // z = first half of sigmoid(z_r)
    xsr[2 + j] = s;
  }
  // write xs (bf16) into Acat slots [0,80) (66 real + 14 zero pad)
  {
    unsigned short a16[80];
#pragma unroll
    for (int c = 0; c < CC; ++c) a16[c] = f2bf(xsr[c]);
#pragma unroll
    for (int c = CC; c < 80; ++c) a16[c] = 0;
#pragma unroll
    for (int k = 0; k < 10; ++k) {
      unsigned int q0 = (unsigned int)a16[8 * k + 0] | ((unsigned int)a16[8 * k + 1] << 16);
      unsigned int q1 = (unsigned int)a16[8 * k + 2] | ((unsigned int)a16[8 * k + 3] << 16);
      unsigned int q2 = (unsigned int)a16[8 * k + 4] | ((unsigned int)a16[8 * k + 5] << 16);
      unsigned int q3 = (unsigned int)a16[8 * k + 6] | ((unsigned int)a16[8 * k + 7] << 16);
      *(uint4*)&Acat[(size_t)bn * KP + 8 * k] = make_uint4(q0, q1, q2, q3);
    }
  }

  float h1[16];
#pragma unroll
  for (int j = 0; j < 16; ++j) h1[j] = b1[j];
#pragma unroll
  for (int i = 0; i < CC; ++i) {
    float xv = xsr[i];
#pragma unroll
    for (int j = 0; j < 16; ++j) h1[j] = fmaf(xv, w1[i * 16 + j], h1[j]);
  }
#pragma unroll
  for (int j = 0; j < 16; ++j) h1[j] = sigmoidf_(h1[j]);

  float h2[2];
#pragma unroll
  for (int j = 0; j < 2; ++j) {
    float s = b2[j];
#pragma unroll
    for (int i = 0; i < 16; ++i) s = fmaf(h1[i], w2[i * 2 + j], s);
    h2[j] = sigmoidf_(s);
  }

  unsigned short nv16[16];
#pragma unroll
  for (int e = 0; e < EE; ++e) {
    float f = b3[e] + h2[0] * w3[e] + h2[1] * w3[EE + e];
    int be = bn * EE + e;
    float dyn = emb[n * EE + e] * tme[be] * day[be] * spd[be] * occ[be];
    nv16[e] = f2bf(tanhf(dyn * f));
  }
#pragma unroll
  for (int e = EE; e < 16; ++e) nv16[e] = 0;
  unsigned int w[8];
#pragma unroll
  for (int k = 0; k < 8; ++k)
    w[k] = (unsigned int)nv16[2 * k] | ((unsigned int)nv16[2 * k + 1] << 16);
  *(uint4*)&nv2[slot]     = make_uint4(w[0], w[1], w[2], w[3]);
  *(uint4*)&nv2[slot + 8] = make_uint4(w[4], w[5], w[6], w[7]);
}

// ---------------- K2: degree via MFMA + fused rsqrt + xsd2 build ----------------
// grid (14, 64), 256 thr = 4 waves; wave w owns n-rows [nt*64+w*16, +16)
__global__ __launch_bounds__(256) void k2_deg(const unsigned short* __restrict__ nv2,
                                              const unsigned short* __restrict__ Acat,
                                              float* __restrict__ d_g,
                                              unsigned short* __restrict__ xsd2) {
  int nt = blockIdx.x, b = blockIdx.y;
  int t = threadIdx.x, wid = t >> 6, lane = t & 63;
  int col = lane & 15, q = lane >> 4;
  __shared__ float tile[64][67];
  __shared__ float d_s[64];

  const unsigned short* nvb = nv2 + (size_t)b * NT16 * 32 * 8;
  bf16x8 zf = {0, 0, 0, 0, 0, 0, 0, 0};
  bf16x8 anv = zf;
  if (q < 2) anv = *(const bf16x8*)&nvb[((size_t)(nt * 4 + wid) * 32 + col * 2 + q) * 8];

  float rs[4] = {0.f, 0.f, 0.f, 0.f};
  bf16x8 cur = zf, nxt = zf;
  if (q < 2) cur = *(const bf16x8*)&nvb[((size_t)0 * 32 + col * 2 + q) * 8];
  for (int mt = 0; mt < NT16; ++mt) {
    if (q < 2 && mt + 1 < NT16)
      nxt = *(const bf16x8*)&nvb[((size_t)(mt + 1) * 32 + col * 2 + q) * 8];
    f32x4 z = {0.f, 0.f, 0.f, 0.f};
    f32x4 g = __builtin_amdgcn_mfma_f32_16x16x32_bf16(anv, cur, z, 0, 0, 0);
#pragma unroll
    for (int r = 0; r < 4; ++r) rs[r] += fmaxf(g[r], 0.f);
    cur = nxt;
  }
#pragma unroll
  for (int off = 1; off < 16; off <<= 1) {
#pragma unroll
    for (int r = 0; r < 4; ++r) rs[r] += __shfl_xor(rs[r], off);
  }
  if (col == 0) {
#pragma unroll
    for (int r = 0; r < 4; ++r) {
      int n = nt * 64 + wid * 16 + q * 4 + r;
      float dv = (n < NN) ? rsqrtf(rs[r]) : 0.f;
      d_g[b * NP + n] = dv;
      d_s[wid * 16 + q * 4 + r] = dv;
    }
  }
  __syncthreads();

  // fused: xsd2 tiles for this block's 64 m-rows (mbb = 2nt, 2nt+1)
  int mb = nt * 64;
  for (int idx = t; idx < 64 * CC; idx += 256) {
    int ml = idx / CC, c = idx - ml * CC;
    int m = mb + ml;
    float v = 0.f;
    if (m < NN) v = bf2f(Acat[((size_t)(b * NN + m)) * KP + c]);
    tile[ml][c] = v * d_s[ml];
  }
  __syncthreads();
  for (int idx = t; idx < 2 * 5 * 4 * 16; idx += 256) {
    int colw = idx & 15;
    int qw = (idx >> 4) & 3;
    int ctw = (idx >> 6) % 5;
    int mbbl = idx / (16 * 4 * 5);
    unsigned int o[4];
#pragma unroll
    for (int jj = 0; jj < 4; ++jj) {
      int ml = mbbl * 32 + qw * 8 + jj * 2;
      int c = ctw * 16 + colw;
      float v0 = (c < CC) ? tile[ml][c] : 0.f;
      float v1 = (c < CC) ? tile[ml + 1][c] : 0.f;
      o[jj] = (unsigned int)f2bf(v0) | ((unsigned int)f2bf(v1) << 16);
    }
    size_t dst = (((((size_t)b * MB32 + (nt * 2 + mbbl)) * 5 + ctw) * 4 + qw) * 16 + colw) * 8;
    *(uint4*)&xsd2[dst] = make_uint4(o[0], o[1], o[2], o[3]);
  }
}

// ---------------- K3: Acat[bn][80+c] = -d[n] * sum_m relu(nv.nv)[n,m] * xsd[m,c] -----
// No LDS, no barriers: stage1 transposed MFMA -> relu/pack -> 8x __shfl lane
// transform -> stage2 MFMA. All fragment loads coalesced (tiled layouts).
__global__ __launch_bounds__(256) void k3_agg(const unsigned short* __restrict__ nv2,
                                              const float* __restrict__ d_g,
                                              const unsigned short* __restrict__ xsd2,
                                              unsigned short* __restrict__ Acat) {
  int nt = blockIdx.x, b = blockIdx.y, t = threadIdx.x;
  int wid = t >> 6, lane = t & 63, col = lane & 15, q = lane >> 4;
  int n16 = nt * 64 + wid * 16;

  const unsigned short* nvb = nv2 + (size_t)b * NT16 * 32 * 8;
  const unsigned short* xb = xsd2 + (size_t)b * MB32 * 5 * 4 * 16 * 8;

  bf16x8 zf = {0, 0, 0, 0, 0, 0, 0, 0};
  bf16x8 anv = zf;
  if (q < 2) anv = *(const bf16x8*)&nvb[((size_t)(nt * 4 + wid) * 32 + col * 2 + q) * 8];

  f32x4 acc[5];
#pragma unroll
  for (int ct = 0; ct < 5; ++ct) acc[ct] = (f32x4){0.f, 0.f, 0.f, 0.f};

  int base = ((q & 1) << 5) + col;   // shfl source lane base
  bool hi = (q >= 2);

  for (int i = 0; i < MB32; ++i) {
    // nv m-frags: tiles 2i, 2i+1 (coalesced 512B)
    bf16x8 b0 = zf, b1 = zf;
    if (q < 2) {
      b0 = *(const bf16x8*)&nvb[((size_t)(i * 2) * 32 + col * 2 + q) * 8];
      b1 = *(const bf16x8*)&nvb[((size_t)(i * 2 + 1) * 32 + col * 2 + q) * 8];
    }
    // xsd frags (coalesced 1KB each)
    bf16x8 xf[5];
#pragma unroll
    for (int ct = 0; ct < 5; ++ct)
      xf[ct] = *(const bf16x8*)&xb[((((size_t)i * 5 + ct) * 4 + q) * 16 + col) * 8];

    // stage1 transposed: lane holds G1T[m = q*4+r][n = col]
    f32x4 z = {0.f, 0.f, 0.f, 0.f};
    f32x4 g0 = __builtin_amdgcn_mfma_f32_16x16x32_bf16(b0, anv, z, 0, 0, 0);
    f32x4 g1 = __builtin_amdgcn_mfma_f32_16x16x32_bf16(b1, anv, z, 0, 0, 0);
    unsigned int p00 = pkrelu(g0[0], g0[1]), p01 = pkrelu(g0[2], g0[3]);
    unsigned int p10 = pkrelu(g1[0], g1[1]), p11 = pkrelu(g1[2], g1[3]);
    // lane transform C-layout -> A-operand layout: dest(col,q) k=q*8+t needs
    // src lane ((q&1)*2 + t/4)*16 + col, reg pair (t/2)&1
    unsigned int s00 = (unsigned int)__shfl((int)p00, base);
    unsigned int s01 = (unsigned int)__shfl((int)p01, base);
    unsigned int s02 = (unsigned int)__shfl((int)p00, base + 16);
    unsigned int s03 = (unsigned int)__shfl((int)p01, base + 16);
    unsigned int s10 = (unsigned int)__shfl((int)p10, base);
    unsigned int s11 = (unsigned int)__shfl((int)p11, base);
    unsigned int s12 = (unsigned int)__shfl((int)p10, base + 16);
    unsigned int s13 = (unsigned int)__shfl((int)p11, base + 16);
    union { unsigned int u[4]; bf16x8 v; } cv;
    cv.u[0] = hi ? s10 : s00;
    cv.u[1] = hi ? s11 : s01;
    cv.u[2] = hi ? s12 : s02;
    cv.u[3] = hi ? s13 : s03;

    // stage2
#pragma unroll
    for (int ct = 0; ct < 5; ++ct)
      acc[ct] = __builtin_amdgcn_mfma_f32_16x16x32_bf16(cv.v, xf[ct], acc[ct], 0, 0, 0);
  }

  float dn[4];
#pragma unroll
  for (int r = 0; r < 4; ++r) dn[r] = d_g[b * NP + n16 + q * 4 + r];
#pragma unroll
  for (int ct = 0; ct < 5; ++ct) {
    int c = ct * 16 + col;   // c in [0,80): zeros beyond 65 land in the pad slots
#pragma unroll
    for (int r = 0; r < 4; ++r) {
      int n = n16 + q * 4 + r;
      if (n < NN)
        Acat[((size_t)(b * NN) + n) * KP + 80 + c] = f2bf(-(acc[ct][r] * dn[r]));
    }
  }
}

// ---------------- K4b: out[b,o] = act( A'[b,:] . W'[o,:] + bias[o] ) via MFMA --------
// grid (NN); 256 thr = 4 waves (wave = 16 b-rows); W' built in LDS per block
template<int OT, bool GATE>
__global__ __launch_bounds__(256) void k4b_gemm(
    const float* __restrict__ emb, const float* __restrict__ wpool,
    const float* __restrict__ bpool, const unsigned short* __restrict__ Acat,
    float* __restrict__ zr_w,
    const float* __restrict__ state, const float* __restrict__ zr_r,
    float* __restrict__ out) {
  int n = blockIdx.x, t = threadIdx.x;
  __shared__ __align__(16) unsigned short Ws[OT * 168];  // [o][k], 84-word rows
  __shared__ float bias_s[OT];

  // ---- W' build: W0+W1 at k=i, W1 at k=80+i ----
  const int OG = OT / 4;            // o-groups of 4 (float4 over o)
  int og = t % OG, ti = t / OG;     // ti strides i
  int o4 = og * 4;
  float em[EE];
#pragma unroll
  for (int e = 0; e < EE; ++e) em[e] = emb[n * EE + e];

  for (int i = ti; i < CC; i += 256 / OG) {
    float4 s0 = make_float4(0.f, 0.f, 0.f, 0.f);
    float4 s1 = make_float4(0.f, 0.f, 0.f, 0.f);
#pragma unroll
    for (int e = 0; e < EE; ++e) {
      float4 w0 = *(const float4*)&wpool[(((size_t)(e * 2 + 0) * CC + i)) * OT + o4];
      float4 w1 = *(const float4*)&wpool[(((size_t)(e * 2 + 1) * CC + i)) * OT + o4];
      s0.x = fmaf(em[e], w0.x, s0.x); s0.y = fmaf(em[e], w0.y, s0.y);
      s0.z = fmaf(em[e], w0.z, s0.z); s0.w = fmaf(em[e], w0.w, s0.w);
      s1.x = fmaf(em[e], w1.x, s1.x); s1.y = fmaf(em[e], w1.y, s1.y);
      s1.z = fmaf(em[e], w1.z, s1.z); s1.w = fmaf(em[e], w1.w, s1.w);
    }
    Ws[(o4 + 0) * 168 + i] = f2bf(s0.x + s1.x);
    Ws[(o4 + 1) * 168 + i] = f2bf(s0.y + s1.y);
    Ws[(o4 + 2) * 168 + i] = f2bf(s0.z + s1.z);
    Ws[(o4 + 3) * 168 + i] = f2bf(s0.w + s1.w);
    Ws[(o4 + 0) * 168 + 80 + i] = f2bf(s1.x);
    Ws[(o4 + 1) * 168 + 80 + i] = f2bf(s1.y);
    Ws[(o4 + 2) * 168 + 80 + i] = f2bf(s1.z);
    Ws[(o4 + 3) * 168 + 80 + i] = f2bf(s1.w);
  }
  // zero pad slots k in [66,80) and [146,160)
  for (int idx = t; idx < OT * 14; idx += 256) {
    int o = idx / 14, kk = idx - o * 14;
    Ws[o * 168 + 66 + kk] = 0;
    Ws[o * 168 + 146 + kk] = 0;
  }
  if (t < OT) {
    float s = 0.f;
#pragma unroll
    for (int e = 0; e < EE; ++e) s = fmaf(em[e], bpool[e * OT + t], s);
    bias_s[t] = s;
  }
  __syncthreads();

  // ---- GEMM: 4 waves x (16b x OT), K=160 ----
  int wid = t >> 6, lane = t & 63, col = lane & 15, q = lane >> 4;
  int bA = wid * 16 + col;   // A-frag row = batch index
  f32x4 acc[OT / 16];
#pragma unroll
  for (int ot = 0; ot < OT / 16; ++ot) acc[ot] = (f32x4){0.f, 0.f, 0.f, 0.f};

#pragma unroll
  for (int ks = 0; ks < 5; ++ks) {
    bf16x8 af = *(const bf16x8*)&Acat[((size_t)(bA * NN + n)) * KP + ks * 32 + q * 8];
#pragma unroll
    for (int ot = 0; ot < OT / 16; ++ot) {
      bf16x8 bf = *(const bf16x8*)&Ws[(ot * 16 + col) * 168 + ks * 32 + q * 8];
      acc[ot] = __builtin_amdgcn_mfma_f32_16x16x32_bf16(af, bf, acc[ot], 0, 0, 0);
    }
  }

#pragma unroll
  for (int ot = 0; ot < OT / 16; ++ot) {
    int o = ot * 16 + col;
    float bia = bias_s[o];
#pragma unroll
    for (int r = 0; r < 4; ++r) {
      int bb = wid * 16 + q * 4 + r;
      float v = acc[ot][r] + bia;
      if (GATE) {
        zr_w[((size_t)(bb * NN + n)) * 128 + o] = sigmoidf_(v);
      } else {
        float hc = tanhf(v);
        float rr = zr_r[((size_t)(bb * NN + n)) * 128 + 64 + o];
        float st = state[((size_t)(bb * NN + n)) * 64 + o];
        out[((size_t)(bb * NN + n)) * 64 + o] = fmaf(rr, st - hc, hc);
      }
    }
  }
}

extern "C" void kernel_launch(void* const* d_in, const int* in_sizes, int n_in,
                              void* d_out, int out_size, void* d_ws, size_t ws_size,
                              hipStream_t stream) {
  const float* x     = (const float*)d_in[0];
  const float* state = (const float*)d_in[1];
  const float* emb   = (const float*)d_in[2];
  const float* tme   = (const float*)d_in[3];
  const float* day   = (const float*)d_in[4];
  const float* spd   = (const float*)d_in[5];
  const float* occ   = (const float*)d_in[6];
  const float* gwp   = (const float*)d_in[7];
  const float* gbp   = (const float*)d_in[8];
  const float* gw1   = (const float*)d_in[9];
  const float* gb1   = (const float*)d_in[10];
  const float* gw2   = (const float*)d_in[11];
  const float* gb2   = (const float*)d_in[12];
  const float* gw3   = (const float*)d_in[13];
  const float* gb3   = (const float*)d_in[14];
  const float* uwp   = (const float*)d_in[15];
  const float* ubp   = (const float*)d_in[16];
  const float* uw1   = (const float*)d_in[17];
  const float* ub1   = (const float*)d_in[18];
  const float* uw2   = (const float*)d_in[19];
  const float* ub2   = (const float*)d_in[20];
  const float* uw3   = (const float*)d_in[21];
  const float* ub3   = (const float*)d_in[22];

  char* w = (char*)d_ws;
  unsigned short* Acat = (unsigned short*)w;  w += (size_t)BB * NN * KP * 2;        // 18.08 MB
  unsigned short* nv2  = (unsigned short*)w;  w += (size_t)BB * NT16 * 32 * 8 * 2;  // 1.84 MB
  unsigned short* xsd2 = (unsigned short*)w;  w += (size_t)BB * MB32 * 5 * 4 * 16 * 8 * 2;  // 9.18 MB
  float* d_g  = (float*)w;  w += (size_t)BB * NP * 4;
  float* zr   = (float*)w;  w += (size_t)BB * NN * 128 * 4;                         // 28.93 MB

  dim3 b256(256);
  dim3 gK1((BB * NP) / 256);      // 224
  dim3 gK2(14, BB);
  dim3 gK4(NN);

  // phase A (gate)
  k1_hyper<0><<<gK1, b256, 0, stream>>>(x, state, zr, emb, tme, day, spd, occ,
                                        gw1, gb1, gw2, gb2, gw3, gb3, Acat, nv2);
  k2_deg<<<gK2, b256, 0, stream>>>(nv2, Acat, d_g, xsd2);
  k3_agg<<<gK2, b256, 0, stream>>>(nv2, d_g, xsd2, Acat);
  k4b_gemm<128, true><<<gK4, b256, 0, stream>>>(emb, gwp, gbp, Acat, zr,
                                                nullptr, nullptr, nullptr);
  // phase B (update)
  k1_hyper<1><<<gK1, b256, 0, stream>>>(x, state, zr, emb, tme, day, spd, occ,
                                        uw1, ub1, uw2, ub2, uw3, ub3, Acat, nv2);
  k2_deg<<<gK2, b256, 0, stream>>>(nv2, Acat, d_g, xsd2);
  k3_agg<<<gK2, b256, 0, stream>>>(nv2, d_g, xsd2, Acat);
  k4b_gemm<64, false><<<gK4, b256, 0, stream>>>(emb, uwp, ubp, Acat, nullptr,
                                                state, zr, (float*)d_out);
}